// Round 1
// baseline (518.682 us; speedup 1.0000x reference)
//
#include <hip/hip_runtime.h>

// GlobalLinear: per-graph mean of node/edge features, then 3 linear
// projections + bias. Dims fixed by the reference:
//   DN = DG = DO = 128, DE = 64.
// Memory-bound: node_features 256 MB + edge_features 256 MB dominate.

#define DN 128
#define DE 64
#define DO 128
#define NODE_SPLIT 4   // blocks per graph for node aggregation (1000 rows -> 250/blk)
#define EDGE_SPLIT 8   // blocks per graph for edge aggregation (2000 rows -> 250/blk)

// ---------------------------------------------------------------------------
// Kernel 1: exclusive prefix-sum of per-graph lengths -> segment offsets.
// Single block, handles arbitrary G in 512-wide passes with carry.
// ---------------------------------------------------------------------------
__global__ __launch_bounds__(512) void scan_offsets_kernel(
    const int* __restrict__ nlen, const int* __restrict__ elen, int G,
    int* __restrict__ noff, int* __restrict__ eoff)
{
    __shared__ int sn[512], se[512];
    __shared__ int carry_n, carry_e;
    const int t = threadIdx.x;
    if (t == 0) { carry_n = 0; carry_e = 0; }
    __syncthreads();

    for (int base = 0; base < G; base += 512) {
        const int idx = base + t;
        const int vn = (idx < G) ? nlen[idx] : 0;
        const int ve = (idx < G) ? elen[idx] : 0;
        sn[t] = vn; se[t] = ve;
        __syncthreads();
        // Hillis-Steele inclusive scan
        for (int off = 1; off < 512; off <<= 1) {
            const int an = (t >= off) ? sn[t - off] : 0;
            const int ae = (t >= off) ? se[t - off] : 0;
            __syncthreads();
            sn[t] += an; se[t] += ae;
            __syncthreads();
        }
        if (idx < G) {
            noff[idx] = carry_n + sn[t] - vn;   // exclusive
            eoff[idx] = carry_e + se[t] - ve;
        }
        __syncthreads();
        if (t == 0) {
            const int last = (G - base < 512) ? (G - base - 1) : 511;
            carry_n += sn[last];
            carry_e += se[last];
        }
        __syncthreads();
    }
}

// ---------------------------------------------------------------------------
// Kernel 2: fused node+edge segment-sum.
// Node blocks: 256 thr = 32 col-lanes (float4 over 128 cols) x 8 row-lanes.
// Edge blocks: 256 thr = 16 col-lanes (float4 over  64 cols) x 16 row-lanes.
// LDS tree-reduce over row-lanes, then atomicAdd partials into workspace.
// ---------------------------------------------------------------------------
__global__ __launch_bounds__(256) void agg_kernel(
    const float* __restrict__ nodes, const float* __restrict__ edges,
    const int* __restrict__ noff, const int* __restrict__ eoff,
    const int* __restrict__ nlen, const int* __restrict__ elen,
    float* __restrict__ nsum, float* __restrict__ esum, int G)
{
    __shared__ float4 sm[256];
    const int b = blockIdx.x;
    const int t = threadIdx.x;

    if (b < G * NODE_SPLIT) {
        // ---- node aggregation chunk ----
        const int g = b / NODE_SPLIT;
        const int c = b % NODE_SPLIT;
        const int len = nlen[g];
        const int off = noff[g];
        const int chunk = (len + NODE_SPLIT - 1) / NODE_SPLIT;
        const int r0 = c * chunk;
        const int r1 = (r0 + chunk < len) ? (r0 + chunk) : len;

        const int col = t & 31;        // float4 column index: 32*4 = 128 cols
        const int rl  = t >> 5;        // 8 row lanes
        float4 acc = make_float4(0.f, 0.f, 0.f, 0.f);
        const float4* __restrict__ base = (const float4*)nodes; // row = 32 float4
        for (int r = r0 + rl; r < r1; r += 8) {
            const float4 v = base[(size_t)(off + r) * (DN / 4) + col];
            acc.x += v.x; acc.y += v.y; acc.z += v.z; acc.w += v.w;
        }
        sm[t] = acc;
        __syncthreads();
        for (int s = 128; s >= 32; s >>= 1) {
            if (t < s) {
                const float4 o = sm[t + s];
                sm[t].x += o.x; sm[t].y += o.y; sm[t].z += o.z; sm[t].w += o.w;
            }
            __syncthreads();
        }
        if (t < 32) {
            const float4 v = sm[t];
            float* dst = &nsum[(size_t)g * DN + col * 4];
            atomicAdd(dst + 0, v.x);
            atomicAdd(dst + 1, v.y);
            atomicAdd(dst + 2, v.z);
            atomicAdd(dst + 3, v.w);
        }
    } else {
        // ---- edge aggregation chunk ----
        const int bb = b - G * NODE_SPLIT;
        const int g = bb / EDGE_SPLIT;
        const int c = bb % EDGE_SPLIT;
        const int len = elen[g];
        const int off = eoff[g];
        const int chunk = (len + EDGE_SPLIT - 1) / EDGE_SPLIT;
        const int r0 = c * chunk;
        const int r1 = (r0 + chunk < len) ? (r0 + chunk) : len;

        const int col = t & 15;        // float4 column index: 16*4 = 64 cols
        const int rl  = t >> 4;        // 16 row lanes
        float4 acc = make_float4(0.f, 0.f, 0.f, 0.f);
        const float4* __restrict__ base = (const float4*)edges; // row = 16 float4
        for (int r = r0 + rl; r < r1; r += 16) {
            const float4 v = base[(size_t)(off + r) * (DE / 4) + col];
            acc.x += v.x; acc.y += v.y; acc.z += v.z; acc.w += v.w;
        }
        sm[t] = acc;
        __syncthreads();
        for (int s = 128; s >= 16; s >>= 1) {
            if (t < s) {
                const float4 o = sm[t + s];
                sm[t].x += o.x; sm[t].y += o.y; sm[t].z += o.z; sm[t].w += o.w;
            }
            __syncthreads();
        }
        if (t < 16) {
            const float4 v = sm[t];
            float* dst = &esum[(size_t)g * DE + col * 4];
            atomicAdd(dst + 0, v.x);
            atomicAdd(dst + 1, v.y);
            atomicAdd(dst + 2, v.z);
            atomicAdd(dst + 3, v.w);
        }
    }
}

// ---------------------------------------------------------------------------
// Kernel 3: out[g,o] = mean_n(g)·Wn[o] + mean_e(g)·We[o] + glob[g]·Wg[o] + bias[o]
// One block per graph, 128 threads (one per output channel).
// ---------------------------------------------------------------------------
__global__ __launch_bounds__(128) void finalize_kernel(
    const float* __restrict__ nsum, const float* __restrict__ esum,
    const float* __restrict__ glob,
    const float* __restrict__ Wn, const float* __restrict__ We,
    const float* __restrict__ Wg, const float* __restrict__ bias,
    const int* __restrict__ nlen, const int* __restrict__ elen,
    float* __restrict__ out)
{
    __shared__ float sn[DN], se_[DE], sg[DN];
    const int g = blockIdx.x;
    const int o = threadIdx.x;

    const int nl = nlen[g];
    const int el = elen[g];
    const float inv_n = 1.0f / (float)((nl > 1) ? nl : 1);
    const float inv_e = 1.0f / (float)((el > 1) ? el : 1);

    sn[o] = nsum[(size_t)g * DN + o] * inv_n;
    sg[o] = glob[(size_t)g * DN + o];
    if (o < DE) se_[o] = esum[(size_t)g * DE + o] * inv_e;
    __syncthreads();

    float acc = bias[o];
    const float4* __restrict__ wn = (const float4*)(Wn + (size_t)o * DN);
    const float4* __restrict__ wg = (const float4*)(Wg + (size_t)o * DN);
    const float4* __restrict__ we = (const float4*)(We + (size_t)o * DE);
    const float4* s4n = (const float4*)sn;
    const float4* s4g = (const float4*)sg;
    const float4* s4e = (const float4*)se_;

    #pragma unroll
    for (int i = 0; i < DN / 4; ++i) {
        const float4 a = wn[i], v = s4n[i];
        acc += a.x * v.x + a.y * v.y + a.z * v.z + a.w * v.w;
    }
    #pragma unroll
    for (int i = 0; i < DN / 4; ++i) {
        const float4 a = wg[i], v = s4g[i];
        acc += a.x * v.x + a.y * v.y + a.z * v.z + a.w * v.w;
    }
    #pragma unroll
    for (int i = 0; i < DE / 4; ++i) {
        const float4 a = we[i], v = s4e[i];
        acc += a.x * v.x + a.y * v.y + a.z * v.z + a.w * v.w;
    }
    out[(size_t)g * DO + o] = acc;
}

// ---------------------------------------------------------------------------
extern "C" void kernel_launch(void* const* d_in, const int* in_sizes, int n_in,
                              void* d_out, int out_size, void* d_ws, size_t ws_size,
                              hipStream_t stream)
{
    const float* nodes = (const float*)d_in[0];
    const float* edges = (const float*)d_in[1];
    const float* glob  = (const float*)d_in[2];
    const float* Wn    = (const float*)d_in[3];
    const float* We    = (const float*)d_in[4];
    const float* Wg    = (const float*)d_in[5];
    const float* bias  = (const float*)d_in[6];
    const int*   nlen  = (const int*)d_in[7];
    const int*   elen  = (const int*)d_in[8];
    float*       out   = (float*)d_out;

    const int G = in_sizes[7];           // 500

    // workspace layout: nsum[G*128] | esum[G*64] | noff[G] | eoff[G]
    float* nsum = (float*)d_ws;
    float* esum = nsum + (size_t)G * DN;
    int*   noff = (int*)(esum + (size_t)G * DE);
    int*   eoff = noff + G;

    hipMemsetAsync(d_ws, 0, (size_t)G * (DN + DE) * sizeof(float), stream);

    scan_offsets_kernel<<<1, 512, 0, stream>>>(nlen, elen, G, noff, eoff);

    const int agg_blocks = G * (NODE_SPLIT + EDGE_SPLIT);
    agg_kernel<<<agg_blocks, 256, 0, stream>>>(nodes, edges, noff, eoff,
                                               nlen, elen, nsum, esum, G);

    finalize_kernel<<<G, 128, 0, stream>>>(nsum, esum, glob, Wn, We, Wg, bias,
                                           nlen, elen, out);
}

// Round 2
// 516.921 us; speedup vs baseline: 1.0034x; 1.0034x over previous
//
#include <hip/hip_runtime.h>

// GlobalLinear: per-graph mean of node/edge features, then 3 linear
// projections + bias. Dims fixed by the reference:
//   DN = DG = DO = 128, DE = 64.
// Memory-bound: node_features 256 MB + edge_features 256 MB dominate.
// R1 lesson: 1 outstanding load/thread is latency-bound (1.7 TB/s HBM).
// R2: unroll x4 with independent accumulators -> 4 loads in flight/thread.

#define DN 128
#define DE 64
#define DO 128
#define NODE_SPLIT 4   // blocks per graph for node aggregation (1000 rows -> 250/blk)
#define EDGE_SPLIT 8   // blocks per graph for edge aggregation (2000 rows -> 250/blk)

// ---------------------------------------------------------------------------
// Kernel 1: exclusive prefix-sum of per-graph lengths -> segment offsets.
// ---------------------------------------------------------------------------
__global__ __launch_bounds__(512) void scan_offsets_kernel(
    const int* __restrict__ nlen, const int* __restrict__ elen, int G,
    int* __restrict__ noff, int* __restrict__ eoff)
{
    __shared__ int sn[512], se[512];
    __shared__ int carry_n, carry_e;
    const int t = threadIdx.x;
    if (t == 0) { carry_n = 0; carry_e = 0; }
    __syncthreads();

    for (int base = 0; base < G; base += 512) {
        const int idx = base + t;
        const int vn = (idx < G) ? nlen[idx] : 0;
        const int ve = (idx < G) ? elen[idx] : 0;
        sn[t] = vn; se[t] = ve;
        __syncthreads();
        for (int off = 1; off < 512; off <<= 1) {
            const int an = (t >= off) ? sn[t - off] : 0;
            const int ae = (t >= off) ? se[t - off] : 0;
            __syncthreads();
            sn[t] += an; se[t] += ae;
            __syncthreads();
        }
        if (idx < G) {
            noff[idx] = carry_n + sn[t] - vn;   // exclusive
            eoff[idx] = carry_e + se[t] - ve;
        }
        __syncthreads();
        if (t == 0) {
            const int last = (G - base < 512) ? (G - base - 1) : 511;
            carry_n += sn[last];
            carry_e += se[last];
        }
        __syncthreads();
    }
}

// ---------------------------------------------------------------------------
// Kernel 2: fused node+edge segment-sum, 4-deep ILP per thread.
// Node blocks: 256 thr = 32 col-lanes (float4 over 128 cols) x 8 row-lanes,
//   each thread owns 4 consecutive rows per iteration (group of 32 rows).
// Edge blocks: 256 thr = 16 col-lanes (float4 over  64 cols) x 16 row-lanes,
//   each thread owns 4 consecutive rows per iteration (group of 64 rows).
// LDS tree-reduce over row-lanes, then atomicAdd partials into workspace.
// ---------------------------------------------------------------------------
__global__ __launch_bounds__(256) void agg_kernel(
    const float* __restrict__ nodes, const float* __restrict__ edges,
    const int* __restrict__ noff, const int* __restrict__ eoff,
    const int* __restrict__ nlen, const int* __restrict__ elen,
    float* __restrict__ nsum, float* __restrict__ esum, int G)
{
    __shared__ float4 sm[256];
    const int b = blockIdx.x;
    const int t = threadIdx.x;

    if (b < G * NODE_SPLIT) {
        // ---- node aggregation chunk ----
        const int g = b / NODE_SPLIT;
        const int c = b % NODE_SPLIT;
        const int len = nlen[g];
        const int off = noff[g];
        const int chunk = (len + NODE_SPLIT - 1) / NODE_SPLIT;
        const int r0 = c * chunk;
        const int r1 = (r0 + chunk < len) ? (r0 + chunk) : len;
        const int span = (r1 > r0) ? (r1 - r0) : 0;
        const int main_end = r0 + (span & ~31);   // full 32-row groups

        const int col = t & 31;        // float4 column index: 32*4 = 128 cols
        const int rl  = t >> 5;        // 8 row lanes
        const float4* __restrict__ base = (const float4*)nodes; // row = 32 float4

        float4 a0 = make_float4(0.f,0.f,0.f,0.f), a1 = a0, a2 = a0, a3 = a0;
        for (int rr = r0 + rl * 4; rr < main_end; rr += 32) {
            const size_t p = (size_t)(off + rr) * (DN / 4) + col;
            const float4 v0 = base[p];
            const float4 v1 = base[p + (DN / 4)];
            const float4 v2 = base[p + 2 * (DN / 4)];
            const float4 v3 = base[p + 3 * (DN / 4)];
            a0.x += v0.x; a0.y += v0.y; a0.z += v0.z; a0.w += v0.w;
            a1.x += v1.x; a1.y += v1.y; a1.z += v1.z; a1.w += v1.w;
            a2.x += v2.x; a2.y += v2.y; a2.z += v2.z; a2.w += v2.w;
            a3.x += v3.x; a3.y += v3.y; a3.z += v3.z; a3.w += v3.w;
        }
        // tail (<32 rows), one row per row-lane per iter
        for (int r = main_end + rl; r < r1; r += 8) {
            const float4 v = base[(size_t)(off + r) * (DN / 4) + col];
            a0.x += v.x; a0.y += v.y; a0.z += v.z; a0.w += v.w;
        }
        float4 acc;
        acc.x = (a0.x + a1.x) + (a2.x + a3.x);
        acc.y = (a0.y + a1.y) + (a2.y + a3.y);
        acc.z = (a0.z + a1.z) + (a2.z + a3.z);
        acc.w = (a0.w + a1.w) + (a2.w + a3.w);

        sm[t] = acc;
        __syncthreads();
        for (int s = 128; s >= 32; s >>= 1) {
            if (t < s) {
                const float4 o = sm[t + s];
                sm[t].x += o.x; sm[t].y += o.y; sm[t].z += o.z; sm[t].w += o.w;
            }
            __syncthreads();
        }
        if (t < 32) {
            const float4 v = sm[t];
            float* dst = &nsum[(size_t)g * DN + col * 4];
            atomicAdd(dst + 0, v.x);
            atomicAdd(dst + 1, v.y);
            atomicAdd(dst + 2, v.z);
            atomicAdd(dst + 3, v.w);
        }
    } else {
        // ---- edge aggregation chunk ----
        const int bb = b - G * NODE_SPLIT;
        const int g = bb / EDGE_SPLIT;
        const int c = bb % EDGE_SPLIT;
        const int len = elen[g];
        const int off = eoff[g];
        const int chunk = (len + EDGE_SPLIT - 1) / EDGE_SPLIT;
        const int r0 = c * chunk;
        const int r1 = (r0 + chunk < len) ? (r0 + chunk) : len;
        const int span = (r1 > r0) ? (r1 - r0) : 0;
        const int main_end = r0 + (span & ~63);   // full 64-row groups

        const int col = t & 15;        // float4 column index: 16*4 = 64 cols
        const int rl  = t >> 4;        // 16 row lanes
        const float4* __restrict__ base = (const float4*)edges; // row = 16 float4

        float4 a0 = make_float4(0.f,0.f,0.f,0.f), a1 = a0, a2 = a0, a3 = a0;
        for (int rr = r0 + rl * 4; rr < main_end; rr += 64) {
            const size_t p = (size_t)(off + rr) * (DE / 4) + col;
            const float4 v0 = base[p];
            const float4 v1 = base[p + (DE / 4)];
            const float4 v2 = base[p + 2 * (DE / 4)];
            const float4 v3 = base[p + 3 * (DE / 4)];
            a0.x += v0.x; a0.y += v0.y; a0.z += v0.z; a0.w += v0.w;
            a1.x += v1.x; a1.y += v1.y; a1.z += v1.z; a1.w += v1.w;
            a2.x += v2.x; a2.y += v2.y; a2.z += v2.z; a2.w += v2.w;
            a3.x += v3.x; a3.y += v3.y; a3.z += v3.z; a3.w += v3.w;
        }
        // tail (<64 rows), one row per row-lane per iter
        for (int r = main_end + rl; r < r1; r += 16) {
            const float4 v = base[(size_t)(off + r) * (DE / 4) + col];
            a0.x += v.x; a0.y += v.y; a0.z += v.z; a0.w += v.w;
        }
        float4 acc;
        acc.x = (a0.x + a1.x) + (a2.x + a3.x);
        acc.y = (a0.y + a1.y) + (a2.y + a3.y);
        acc.z = (a0.z + a1.z) + (a2.z + a3.z);
        acc.w = (a0.w + a1.w) + (a2.w + a3.w);

        sm[t] = acc;
        __syncthreads();
        for (int s = 128; s >= 16; s >>= 1) {
            if (t < s) {
                const float4 o = sm[t + s];
                sm[t].x += o.x; sm[t].y += o.y; sm[t].z += o.z; sm[t].w += o.w;
            }
            __syncthreads();
        }
        if (t < 16) {
            const float4 v = sm[t];
            float* dst = &esum[(size_t)g * DE + col * 4];
            atomicAdd(dst + 0, v.x);
            atomicAdd(dst + 1, v.y);
            atomicAdd(dst + 2, v.z);
            atomicAdd(dst + 3, v.w);
        }
    }
}

// ---------------------------------------------------------------------------
// Kernel 3: out[g,o] = mean_n(g)·Wn[o] + mean_e(g)·We[o] + glob[g]·Wg[o] + bias[o]
// ---------------------------------------------------------------------------
__global__ __launch_bounds__(128) void finalize_kernel(
    const float* __restrict__ nsum, const float* __restrict__ esum,
    const float* __restrict__ glob,
    const float* __restrict__ Wn, const float* __restrict__ We,
    const float* __restrict__ Wg, const float* __restrict__ bias,
    const int* __restrict__ nlen, const int* __restrict__ elen,
    float* __restrict__ out)
{
    __shared__ float sn[DN], se_[DE], sg[DN];
    const int g = blockIdx.x;
    const int o = threadIdx.x;

    const int nl = nlen[g];
    const int el = elen[g];
    const float inv_n = 1.0f / (float)((nl > 1) ? nl : 1);
    const float inv_e = 1.0f / (float)((el > 1) ? el : 1);

    sn[o] = nsum[(size_t)g * DN + o] * inv_n;
    sg[o] = glob[(size_t)g * DN + o];
    if (o < DE) se_[o] = esum[(size_t)g * DE + o] * inv_e;
    __syncthreads();

    float acc = bias[o];
    const float4* __restrict__ wn = (const float4*)(Wn + (size_t)o * DN);
    const float4* __restrict__ wg = (const float4*)(Wg + (size_t)o * DN);
    const float4* __restrict__ we = (const float4*)(We + (size_t)o * DE);
    const float4* s4n = (const float4*)sn;
    const float4* s4g = (const float4*)sg;
    const float4* s4e = (const float4*)se_;

    #pragma unroll
    for (int i = 0; i < DN / 4; ++i) {
        const float4 a = wn[i], v = s4n[i];
        acc += a.x * v.x + a.y * v.y + a.z * v.z + a.w * v.w;
    }
    #pragma unroll
    for (int i = 0; i < DN / 4; ++i) {
        const float4 a = wg[i], v = s4g[i];
        acc += a.x * v.x + a.y * v.y + a.z * v.z + a.w * v.w;
    }
    #pragma unroll
    for (int i = 0; i < DE / 4; ++i) {
        const float4 a = we[i], v = s4e[i];
        acc += a.x * v.x + a.y * v.y + a.z * v.z + a.w * v.w;
    }
    out[(size_t)g * DO + o] = acc;
}

// ---------------------------------------------------------------------------
extern "C" void kernel_launch(void* const* d_in, const int* in_sizes, int n_in,
                              void* d_out, int out_size, void* d_ws, size_t ws_size,
                              hipStream_t stream)
{
    const float* nodes = (const float*)d_in[0];
    const float* edges = (const float*)d_in[1];
    const float* glob  = (const float*)d_in[2];
    const float* Wn    = (const float*)d_in[3];
    const float* We    = (const float*)d_in[4];
    const float* Wg    = (const float*)d_in[5];
    const float* bias  = (const float*)d_in[6];
    const int*   nlen  = (const int*)d_in[7];
    const int*   elen  = (const int*)d_in[8];
    float*       out   = (float*)d_out;

    const int G = in_sizes[7];           // 500

    // workspace layout: nsum[G*128] | esum[G*64] | noff[G] | eoff[G]
    float* nsum = (float*)d_ws;
    float* esum = nsum + (size_t)G * DN;
    int*   noff = (int*)(esum + (size_t)G * DE);
    int*   eoff = noff + G;

    hipMemsetAsync(d_ws, 0, (size_t)G * (DN + DE) * sizeof(float), stream);

    scan_offsets_kernel<<<1, 512, 0, stream>>>(nlen, elen, G, noff, eoff);

    const int agg_blocks = G * (NODE_SPLIT + EDGE_SPLIT);
    agg_kernel<<<agg_blocks, 256, 0, stream>>>(nodes, edges, noff, eoff,
                                               nlen, elen, nsum, esum, G);

    finalize_kernel<<<G, 128, 0, stream>>>(nsum, esum, glob, Wn, We, Wg, bias,
                                           nlen, elen, out);
}

// Round 3
// 514.537 us; speedup vs baseline: 1.0081x; 1.0046x over previous
//
#include <hip/hip_runtime.h>
#include <stdint.h>

// GlobalLinear: per-graph mean of node/edge features, then 3 linear
// projections + bias. DN = DG = DO = 128, DE = 64. Memory-bound:
// nodes 256 MB + edges 256 MB.
// R1/R2 lesson: plain VGPR-return loads wall at 3.3 TB/s effective
// regardless of per-wave ILP -> suspect per-CU L1/TCP tracker cap.
// R3: stream via global_load_lds DMA ring (8 outstanding 1KB/wave),
// consume own slots with ds_read_b128; no barriers in the hot loop.

#define DN 128
#define DE 64
#define DO 128
#define NCHUNK 4      // chunks per graph per stream (nodes and edges)
#define NW 4          // waves per block (256 threads)
#define SLOTS 8       // outstanding DMA slots per wave, 1 KB each

template<int N> __device__ __forceinline__ void wait_vmcnt() {
    // gfx9 encoding: vmcnt[3:0] | expcnt<<4 | lgkmcnt<<8 | vmcnt[5:4]<<14
    __builtin_amdgcn_s_waitcnt(0x0F70 | (N & 0xF) | ((N >> 4) << 14));
    __asm__ volatile("" ::: "memory");   // keep LDS reads below the wait
}

// ---------------------------------------------------------------------------
// Kernel 1: exclusive prefix-sum of per-graph lengths -> segment offsets.
// ---------------------------------------------------------------------------
__global__ __launch_bounds__(512) void scan_offsets_kernel(
    const int* __restrict__ nlen, const int* __restrict__ elen, int G,
    int* __restrict__ noff, int* __restrict__ eoff)
{
    __shared__ int sn[512], se[512];
    __shared__ int carry_n, carry_e;
    const int t = threadIdx.x;
    if (t == 0) { carry_n = 0; carry_e = 0; }
    __syncthreads();

    for (int base = 0; base < G; base += 512) {
        const int idx = base + t;
        const int vn = (idx < G) ? nlen[idx] : 0;
        const int ve = (idx < G) ? elen[idx] : 0;
        sn[t] = vn; se[t] = ve;
        __syncthreads();
        for (int off = 1; off < 512; off <<= 1) {
            const int an = (t >= off) ? sn[t - off] : 0;
            const int ae = (t >= off) ? se[t - off] : 0;
            __syncthreads();
            sn[t] += an; se[t] += ae;
            __syncthreads();
        }
        if (idx < G) {
            noff[idx] = carry_n + sn[t] - vn;   // exclusive
            eoff[idx] = carry_e + se[t] - ve;
        }
        __syncthreads();
        if (t == 0) {
            const int last = (G - base < 512) ? (G - base - 1) : 511;
            carry_n += sn[last];
            carry_e += se[last];
        }
        __syncthreads();
    }
}

// ---------------------------------------------------------------------------
// Kernel 2: fused node+edge segment-sum via global_load_lds DMA ring.
// Each block owns a contiguous float4 range (multiple of 64 f4 except tail).
// Wave w streams slots s = w, w+4, ... ; each slot = 64 consecutive float4
// (1 KB) DMA'd to wave-private LDS, read back with ds_read_b128, summed.
// Column phase: slot base is 64-f4 aligned and graph base is RF-aligned,
// so lane l always holds column (l % RF). LDS tree-reduce + atomics as before.
// ---------------------------------------------------------------------------
__global__ __launch_bounds__(256) void agg_kernel(
    const float* __restrict__ nodes, const float* __restrict__ edges,
    const int* __restrict__ noff, const int* __restrict__ eoff,
    const int* __restrict__ nlen, const int* __restrict__ elen,
    float* __restrict__ nsum, float* __restrict__ esum, int G)
{
    __shared__ float4 ring[NW * SLOTS * 64];   // 32 KB, reused for tree reduce
    const int b = blockIdx.x;
    const int t = threadIdx.x;
    const int lane = t & 63;
    const int w = t >> 6;

    const bool is_node = (b < G * NCHUNK);
    const int gb = is_node ? b : (b - G * NCHUNK);
    const int g = gb / NCHUNK;
    const int c = gb % NCHUNK;
    const int RF = is_node ? (DN / 4) : (DE / 4);   // float4 per row
    const int len = is_node ? nlen[g] : elen[g];
    const int off = is_node ? noff[g] : eoff[g];
    const float4* __restrict__ src4 =
        (const float4*)(is_node ? nodes : edges);
    float* __restrict__ dst =
        is_node ? &nsum[(size_t)g * DN] : &esum[(size_t)g * DE];

    const size_t fbase = (size_t)off * RF;          // graph base, RF-aligned
    const int span_total = len * RF;
    const int chunk = ((span_total + NCHUNK * 64 - 1) / (NCHUNK * 64)) * 64;
    const int fs = c * chunk;
    int fe = fs + chunk; if (fe > span_total) fe = span_total;
    const int span = (fe > fs) ? (fe - fs) : 0;
    const int nslots = span >> 6;
    const int rem = span & 63;

    // this wave's slot count (slots s with s % NW == w)
    const int ns_w = (nslots > w) ? ((nslots - w + NW - 1) / NW) : 0;

    char* ringc = (char*)ring;

    auto issue = [&](int k) {
        const int s = w + k * NW;
        const float4* gp = src4 + fbase + (size_t)fs + (size_t)s * 64 + lane;
        __builtin_amdgcn_global_load_lds(
            (const __attribute__((address_space(1))) void*)gp,
            (__attribute__((address_space(3))) void*)
                (ringc + (((w * SLOTS) + (k % SLOTS)) << 10)),
            16, 0, 0);
    };
    float4 acc = make_float4(0.f, 0.f, 0.f, 0.f);
    auto consume = [&](int k) {
        const float4* sp =
            (const float4*)(ringc + (((w * SLOTS) + (k % SLOTS)) << 10));
        const float4 v = sp[lane];
        acc.x += v.x; acc.y += v.y; acc.z += v.z; acc.w += v.w;
    };

    const int pre = (ns_w < SLOTS) ? ns_w : SLOTS;
    for (int k = 0; k < pre; ++k) issue(k);

    int k = 0;
    for (; k + SLOTS < ns_w; ++k) {
        wait_vmcnt<SLOTS - 1>();
        consume(k);
        issue(k + SLOTS);     // same ring pos as k; lands >=200cy after ds_read
    }
    {
        const int m = ns_w - k;     // 1..SLOTS outstanding (0 if ns_w==0)
        if (m > 7) { wait_vmcnt<7>(); consume(ns_w - 8); }
        if (m > 6) { wait_vmcnt<6>(); consume(ns_w - 7); }
        if (m > 5) { wait_vmcnt<5>(); consume(ns_w - 6); }
        if (m > 4) { wait_vmcnt<4>(); consume(ns_w - 5); }
        if (m > 3) { wait_vmcnt<3>(); consume(ns_w - 4); }
        if (m > 2) { wait_vmcnt<2>(); consume(ns_w - 3); }
        if (m > 1) { wait_vmcnt<1>(); consume(ns_w - 2); }
        if (m > 0) { wait_vmcnt<0>(); consume(ns_w - 1); }
    }

    // tail (< 64 f4, only when span % 64 != 0): direct atomics
    if (rem && t < rem) {
        const int f = fs + (nslots << 6) + t;
        const float4 v = src4[fbase + f];
        const int col = f & (RF - 1);
        atomicAdd(&dst[col * 4 + 0], v.x);
        atomicAdd(&dst[col * 4 + 1], v.y);
        atomicAdd(&dst[col * 4 + 2], v.z);
        atomicAdd(&dst[col * 4 + 3], v.w);
    }

    __syncthreads();               // all waves done with their ring slots
    float4* sm = ring;             // reuse ring LDS for the tree reduce
    sm[t] = acc;
    __syncthreads();
    const int tmin = RF;           // 32 (nodes) or 16 (edges)
    for (int sdist = 128; sdist >= tmin; sdist >>= 1) {
        if (t < sdist) {
            const float4 o = sm[t + sdist];
            sm[t].x += o.x; sm[t].y += o.y; sm[t].z += o.z; sm[t].w += o.w;
        }
        __syncthreads();
    }
    if (t < RF) {
        const float4 v = sm[t];
        atomicAdd(&dst[t * 4 + 0], v.x);
        atomicAdd(&dst[t * 4 + 1], v.y);
        atomicAdd(&dst[t * 4 + 2], v.z);
        atomicAdd(&dst[t * 4 + 3], v.w);
    }
}

// ---------------------------------------------------------------------------
// Kernel 3: out[g,o] = mean_n(g)·Wn[o] + mean_e(g)·We[o] + glob[g]·Wg[o] + bias[o]
// ---------------------------------------------------------------------------
__global__ __launch_bounds__(128) void finalize_kernel(
    const float* __restrict__ nsum, const float* __restrict__ esum,
    const float* __restrict__ glob,
    const float* __restrict__ Wn, const float* __restrict__ We,
    const float* __restrict__ Wg, const float* __restrict__ bias,
    const int* __restrict__ nlen, const int* __restrict__ elen,
    float* __restrict__ out)
{
    __shared__ float sn[DN], se_[DE], sg[DN];
    const int g = blockIdx.x;
    const int o = threadIdx.x;

    const int nl = nlen[g];
    const int el = elen[g];
    const float inv_n = 1.0f / (float)((nl > 1) ? nl : 1);
    const float inv_e = 1.0f / (float)((el > 1) ? el : 1);

    sn[o] = nsum[(size_t)g * DN + o] * inv_n;
    sg[o] = glob[(size_t)g * DN + o];
    if (o < DE) se_[o] = esum[(size_t)g * DE + o] * inv_e;
    __syncthreads();

    float acc = bias[o];
    const float4* __restrict__ wn = (const float4*)(Wn + (size_t)o * DN);
    const float4* __restrict__ wg = (const float4*)(Wg + (size_t)o * DN);
    const float4* __restrict__ we = (const float4*)(We + (size_t)o * DE);
    const float4* s4n = (const float4*)sn;
    const float4* s4g = (const float4*)sg;
    const float4* s4e = (const float4*)se_;

    #pragma unroll
    for (int i = 0; i < DN / 4; ++i) {
        const float4 a = wn[i], v = s4n[i];
        acc += a.x * v.x + a.y * v.y + a.z * v.z + a.w * v.w;
    }
    #pragma unroll
    for (int i = 0; i < DN / 4; ++i) {
        const float4 a = wg[i], v = s4g[i];
        acc += a.x * v.x + a.y * v.y + a.z * v.z + a.w * v.w;
    }
    #pragma unroll
    for (int i = 0; i < DE / 4; ++i) {
        const float4 a = we[i], v = s4e[i];
        acc += a.x * v.x + a.y * v.y + a.z * v.z + a.w * v.w;
    }
    out[(size_t)g * DO + o] = acc;
}

// ---------------------------------------------------------------------------
extern "C" void kernel_launch(void* const* d_in, const int* in_sizes, int n_in,
                              void* d_out, int out_size, void* d_ws, size_t ws_size,
                              hipStream_t stream)
{
    const float* nodes = (const float*)d_in[0];
    const float* edges = (const float*)d_in[1];
    const float* glob  = (const float*)d_in[2];
    const float* Wn    = (const float*)d_in[3];
    const float* We    = (const float*)d_in[4];
    const float* Wg    = (const float*)d_in[5];
    const float* Wg2   = (const float*)d_in[5];
    const float* bias  = (const float*)d_in[6];
    const int*   nlen  = (const int*)d_in[7];
    const int*   elen  = (const int*)d_in[8];
    float*       out   = (float*)d_out;
    (void)Wg2;

    const int G = in_sizes[7];           // 500

    // workspace layout: nsum[G*128] | esum[G*64] | noff[G] | eoff[G]
    float* nsum = (float*)d_ws;
    float* esum = nsum + (size_t)G * DN;
    int*   noff = (int*)(esum + (size_t)G * DE);
    int*   eoff = noff + G;

    hipMemsetAsync(d_ws, 0, (size_t)G * (DN + DE) * sizeof(float), stream);

    scan_offsets_kernel<<<1, 512, 0, stream>>>(nlen, elen, G, noff, eoff);

    const int agg_blocks = G * NCHUNK * 2;   // node chunks + edge chunks
    agg_kernel<<<agg_blocks, 256, 0, stream>>>(nodes, edges, noff, eoff,
                                               nlen, elen, nsum, esum, G);

    finalize_kernel<<<G, 128, 0, stream>>>(nsum, esum, glob, Wn, We, Wg, bias,
                                           nlen, elen, out);
}

// Round 4
// 482.050 us; speedup vs baseline: 1.0760x; 1.0674x over previous
//
#include <hip/hip_runtime.h>

// GlobalLinear: per-graph mean of node/edge features, then 3 linear
// projections + bias. DN = DG = DO = 128, DE = 64. Memory-bound:
// nodes 256 MB + edges 256 MB compulsory reads.
// R1-R3 lessons: VGPR-return loads (1- and 4-deep) and an 8-deep
// global_load_lds DMA ring ALL wall at ~3.35 TB/s effective read ->
// the limiter is beyond the CU. Theory: harness restore leaves ~256 MB
// of DIRTY input lines in L3; our streaming reads allocate on miss and
// force dirty writebacks, interleaving ~256 MB of writes with ~264 MB
// of reads on HBM. R4: non-temporal loads (nt) -> no allocate on miss,
// no forced writebacks, read-only HBM stream.

#define DN 128
#define DE 64
#define DO 128
#define NODE_SPLIT 4   // blocks per graph for node aggregation
#define EDGE_SPLIT 8   // blocks per graph for edge aggregation

typedef float f4v __attribute__((ext_vector_type(4)));

__device__ __forceinline__ f4v nt_load(const f4v* p) {
    return __builtin_nontemporal_load(p);
}

// ---------------------------------------------------------------------------
// Kernel 1: exclusive prefix-sum of per-graph lengths -> segment offsets.
// ---------------------------------------------------------------------------
__global__ __launch_bounds__(512) void scan_offsets_kernel(
    const int* __restrict__ nlen, const int* __restrict__ elen, int G,
    int* __restrict__ noff, int* __restrict__ eoff)
{
    __shared__ int sn[512], se[512];
    __shared__ int carry_n, carry_e;
    const int t = threadIdx.x;
    if (t == 0) { carry_n = 0; carry_e = 0; }
    __syncthreads();

    for (int base = 0; base < G; base += 512) {
        const int idx = base + t;
        const int vn = (idx < G) ? nlen[idx] : 0;
        const int ve = (idx < G) ? elen[idx] : 0;
        sn[t] = vn; se[t] = ve;
        __syncthreads();
        for (int off = 1; off < 512; off <<= 1) {
            const int an = (t >= off) ? sn[t - off] : 0;
            const int ae = (t >= off) ? se[t - off] : 0;
            __syncthreads();
            sn[t] += an; se[t] += ae;
            __syncthreads();
        }
        if (idx < G) {
            noff[idx] = carry_n + sn[t] - vn;   // exclusive
            eoff[idx] = carry_e + se[t] - ve;
        }
        __syncthreads();
        if (t == 0) {
            const int last = (G - base < 512) ? (G - base - 1) : 511;
            carry_n += sn[last];
            carry_e += se[last];
        }
        __syncthreads();
    }
}

// ---------------------------------------------------------------------------
// Kernel 2: fused node+edge segment-sum, nt float4 loads, 4-deep ILP.
// Node blocks: 256 thr = 32 col-lanes (f4 over 128 cols) x 8 row-lanes.
// Edge blocks: 256 thr = 16 col-lanes (f4 over  64 cols) x 16 row-lanes.
// LDS tree-reduce over row-lanes, then atomicAdd partials into workspace.
// ---------------------------------------------------------------------------
__global__ __launch_bounds__(256) void agg_kernel(
    const float* __restrict__ nodes, const float* __restrict__ edges,
    const int* __restrict__ noff, const int* __restrict__ eoff,
    const int* __restrict__ nlen, const int* __restrict__ elen,
    float* __restrict__ nsum, float* __restrict__ esum, int G)
{
    __shared__ f4v sm[256];
    const int b = blockIdx.x;
    const int t = threadIdx.x;

    if (b < G * NODE_SPLIT) {
        // ---- node aggregation chunk ----
        const int g = b / NODE_SPLIT;
        const int c = b % NODE_SPLIT;
        const int len = nlen[g];
        const int off = noff[g];
        const int chunk = (len + NODE_SPLIT - 1) / NODE_SPLIT;
        const int r0 = c * chunk;
        const int r1 = (r0 + chunk < len) ? (r0 + chunk) : len;
        const int span = (r1 > r0) ? (r1 - r0) : 0;
        const int main_end = r0 + (span & ~31);   // full 32-row groups

        const int col = t & 31;        // f4 column index: 32*4 = 128 cols
        const int rl  = t >> 5;        // 8 row lanes
        const f4v* __restrict__ base = (const f4v*)nodes; // row = 32 f4

        f4v a0 = {0.f,0.f,0.f,0.f}, a1 = a0, a2 = a0, a3 = a0;
        for (int rr = r0 + rl * 4; rr < main_end; rr += 32) {
            const size_t p = (size_t)(off + rr) * (DN / 4) + col;
            a0 += nt_load(base + p);
            a1 += nt_load(base + p + (DN / 4));
            a2 += nt_load(base + p + 2 * (DN / 4));
            a3 += nt_load(base + p + 3 * (DN / 4));
        }
        for (int r = main_end + rl; r < r1; r += 8) {
            a0 += nt_load(base + (size_t)(off + r) * (DN / 4) + col);
        }
        const f4v acc = (a0 + a1) + (a2 + a3);

        sm[t] = acc;
        __syncthreads();
        for (int s = 128; s >= 32; s >>= 1) {
            if (t < s) sm[t] += sm[t + s];
            __syncthreads();
        }
        if (t < 32) {
            const f4v v = sm[t];
            float* dst = &nsum[(size_t)g * DN + col * 4];
            atomicAdd(dst + 0, v.x);
            atomicAdd(dst + 1, v.y);
            atomicAdd(dst + 2, v.z);
            atomicAdd(dst + 3, v.w);
        }
    } else {
        // ---- edge aggregation chunk ----
        const int bb = b - G * NODE_SPLIT;
        const int g = bb / EDGE_SPLIT;
        const int c = bb % EDGE_SPLIT;
        const int len = elen[g];
        const int off = eoff[g];
        const int chunk = (len + EDGE_SPLIT - 1) / EDGE_SPLIT;
        const int r0 = c * chunk;
        const int r1 = (r0 + chunk < len) ? (r0 + chunk) : len;
        const int span = (r1 > r0) ? (r1 - r0) : 0;
        const int main_end = r0 + (span & ~63);   // full 64-row groups

        const int col = t & 15;        // f4 column index: 16*4 = 64 cols
        const int rl  = t >> 4;        // 16 row lanes
        const f4v* __restrict__ base = (const f4v*)edges; // row = 16 f4

        f4v a0 = {0.f,0.f,0.f,0.f}, a1 = a0, a2 = a0, a3 = a0;
        for (int rr = r0 + rl * 4; rr < main_end; rr += 64) {
            const size_t p = (size_t)(off + rr) * (DE / 4) + col;
            a0 += nt_load(base + p);
            a1 += nt_load(base + p + (DE / 4));
            a2 += nt_load(base + p + 2 * (DE / 4));
            a3 += nt_load(base + p + 3 * (DE / 4));
        }
        for (int r = main_end + rl; r < r1; r += 16) {
            a0 += nt_load(base + (size_t)(off + r) * (DE / 4) + col);
        }
        const f4v acc = (a0 + a1) + (a2 + a3);

        sm[t] = acc;
        __syncthreads();
        for (int s = 128; s >= 16; s >>= 1) {
            if (t < s) sm[t] += sm[t + s];
            __syncthreads();
        }
        if (t < 16) {
            const f4v v = sm[t];
            float* dst = &esum[(size_t)g * DE + col * 4];
            atomicAdd(dst + 0, v.x);
            atomicAdd(dst + 1, v.y);
            atomicAdd(dst + 2, v.z);
            atomicAdd(dst + 3, v.w);
        }
    }
}

// ---------------------------------------------------------------------------
// Kernel 3: out[g,o] = mean_n(g)·Wn[o] + mean_e(g)·We[o] + glob[g]·Wg[o] + bias[o]
// ---------------------------------------------------------------------------
__global__ __launch_bounds__(128) void finalize_kernel(
    const float* __restrict__ nsum, const float* __restrict__ esum,
    const float* __restrict__ glob,
    const float* __restrict__ Wn, const float* __restrict__ We,
    const float* __restrict__ Wg, const float* __restrict__ bias,
    const int* __restrict__ nlen, const int* __restrict__ elen,
    float* __restrict__ out)
{
    __shared__ float sn[DN], se_[DE], sg[DN];
    const int g = blockIdx.x;
    const int o = threadIdx.x;

    const int nl = nlen[g];
    const int el = elen[g];
    const float inv_n = 1.0f / (float)((nl > 1) ? nl : 1);
    const float inv_e = 1.0f / (float)((el > 1) ? el : 1);

    sn[o] = nsum[(size_t)g * DN + o] * inv_n;
    sg[o] = glob[(size_t)g * DN + o];
    if (o < DE) se_[o] = esum[(size_t)g * DE + o] * inv_e;
    __syncthreads();

    float acc = bias[o];
    const float4* __restrict__ wn = (const float4*)(Wn + (size_t)o * DN);
    const float4* __restrict__ wg = (const float4*)(Wg + (size_t)o * DN);
    const float4* __restrict__ we = (const float4*)(We + (size_t)o * DE);
    const float4* s4n = (const float4*)sn;
    const float4* s4g = (const float4*)sg;
    const float4* s4e = (const float4*)se_;

    #pragma unroll
    for (int i = 0; i < DN / 4; ++i) {
        const float4 a = wn[i], v = s4n[i];
        acc += a.x * v.x + a.y * v.y + a.z * v.z + a.w * v.w;
    }
    #pragma unroll
    for (int i = 0; i < DN / 4; ++i) {
        const float4 a = wg[i], v = s4g[i];
        acc += a.x * v.x + a.y * v.y + a.z * v.z + a.w * v.w;
    }
    #pragma unroll
    for (int i = 0; i < DE / 4; ++i) {
        const float4 a = we[i], v = s4e[i];
        acc += a.x * v.x + a.y * v.y + a.z * v.z + a.w * v.w;
    }
    out[(size_t)g * DO + o] = acc;
}

// ---------------------------------------------------------------------------
extern "C" void kernel_launch(void* const* d_in, const int* in_sizes, int n_in,
                              void* d_out, int out_size, void* d_ws, size_t ws_size,
                              hipStream_t stream)
{
    const float* nodes = (const float*)d_in[0];
    const float* edges = (const float*)d_in[1];
    const float* glob  = (const float*)d_in[2];
    const float* Wn    = (const float*)d_in[3];
    const float* We    = (const float*)d_in[4];
    const float* Wg    = (const float*)d_in[5];
    const float* bias  = (const float*)d_in[6];
    const int*   nlen  = (const int*)d_in[7];
    const int*   elen  = (const int*)d_in[8];
    float*       out   = (float*)d_out;

    const int G = in_sizes[7];           // 500

    // workspace layout: nsum[G*128] | esum[G*64] | noff[G] | eoff[G]
    float* nsum = (float*)d_ws;
    float* esum = nsum + (size_t)G * DN;
    int*   noff = (int*)(esum + (size_t)G * DE);
    int*   eoff = noff + G;

    hipMemsetAsync(d_ws, 0, (size_t)G * (DN + DE) * sizeof(float), stream);

    scan_offsets_kernel<<<1, 512, 0, stream>>>(nlen, elen, G, noff, eoff);

    const int agg_blocks = G * (NODE_SPLIT + EDGE_SPLIT);
    agg_kernel<<<agg_blocks, 256, 0, stream>>>(nodes, edges, noff, eoff,
                                               nlen, elen, nsum, esum, G);

    finalize_kernel<<<G, 128, 0, stream>>>(nsum, esum, glob, Wn, We, Wg, bias,
                                           nlen, elen, out);
}